// Round 5
// baseline (599.927 us; speedup 1.0000x reference)
//
#include <hip/hip_runtime.h>
#include <hip/hip_bf16.h>

static constexpr int KD  = 64;
static constexpr int KIN = 256;
static constexpr int KH  = 64;

typedef __attribute__((ext_vector_type(8))) short bf16x8;
typedef __attribute__((ext_vector_type(4))) float f32x4;

__device__ inline unsigned short f2bf(float f) {
  union { float f; unsigned u; } uf; uf.f = f;
  unsigned u = uf.u;
  return (unsigned short)((u + 0x7FFFu + ((u >> 16) & 1u)) >> 16);
}
__device__ inline float bf2f(unsigned short h) {
  union { unsigned u; float f; } x; x.u = ((unsigned)h) << 16; return x.f;
}
__device__ inline bf16x8 pack8(const float* p) {
  float4 lo = *(const float4*)p;
  float4 hi = *(const float4*)(p + 4);
  bf16x8 v;
  v[0] = (short)f2bf(lo.x); v[1] = (short)f2bf(lo.y);
  v[2] = (short)f2bf(lo.z); v[3] = (short)f2bf(lo.w);
  v[4] = (short)f2bf(hi.x); v[5] = (short)f2bf(hi.y);
  v[6] = (short)f2bf(hi.z); v[7] = (short)f2bf(hi.w);
  return v;
}
__device__ inline float sigm(float x) { return 1.0f / (1.0f + __expf(-x)); }
__device__ inline float silu_(float x) { return x * sigm(x); }
__device__ inline void atomic_fadd(float* p, float v) {
  asm volatile("global_atomic_add_f32 %0, %1, off" :: "v"(p), "v"(v) : "memory");
}

// ---------------- K0: build frag-major W1 segments + natural W2/Wo transposes ----
// Fragment-major layout: frag block (n,s) holds, at lane l=(p*16+q), elem e:
//   Wseg[k = 32s+8p+e][o = 16n+q]   (A-operand for the transposed MFMA pattern)
__global__ void k_prep(const float* __restrict__ wc1, const float* __restrict__ wg1,
                       const float* __restrict__ wc2, const float* __restrict__ wg2,
                       const float* __restrict__ wo,
                       const float* __restrict__ bc1, const float* __restrict__ bg1,
                       unsigned short* __restrict__ wpb, unsigned short* __restrict__ wpa,
                       unsigned short* __restrict__ wpg,
                       unsigned short* __restrict__ wc2t, unsigned short* __restrict__ wg2t,
                       unsigned short* __restrict__ wot, float* __restrict__ biaspg) {
  int t = blockIdx.x * 256 + threadIdx.x;
  if (t < 16384) {          // wpb: NOUT=256, 32 frag blocks
    int blk = t >> 9, n = blk >> 1, s = blk & 1;
    int lane = (t >> 3) & 63, e = t & 7;
    int p = lane >> 4, q = lane & 15;
    int k = 32 * s + 8 * p + e;      // 0..63
    int o = 16 * n + q;              // 0..255
    float v;
    if (o < 64)       v = wc1[k * KH + o];              // PB1 core  (Wc1 rows 0:64)
    else if (o < 128) v = wg1[k * KH + (o - 64)];       // PB1 gate
    else if (o < 192) v = wc1[(64 + k) * KH + (o - 128)]; // PB2 core (rows 64:128)
    else              v = wg1[(64 + k) * KH + (o - 192)]; // PB2 gate
    wpb[t] = f2bf(v);
  }
  if (t < 8192) {           // wpa / wpg: NOUT=128, 16 frag blocks
    int blk = t >> 9, n = blk >> 1, s = blk & 1;
    int lane = (t >> 3) & 63, e = t & 7;
    int p = lane >> 4, q = lane & 15;
    int k = 32 * s + 8 * p + e;
    int o = 16 * n + q;              // 0..127
    float va = (o < 64) ? wc1[(192 + k) * KH + o] : wg1[(192 + k) * KH + (o - 64)];
    wpa[t] = f2bf(va);               // atom slot: rows 192:256
    float vg = (o < 64) ? wc1[(128 + k) * KH + o] : wg1[(128 + k) * KH + (o - 64)];
    wpg[t] = f2bf(vg);               // angle slot: rows 128:192
  }
  if (t < KH * KD) {        // natural B^T [d][k]
    int d = t >> 6, k = t & 63;
    wc2t[t] = f2bf(wc2[k * KD + d]);
    wg2t[t] = f2bf(wg2[k * KD + d]);
    wot[t]  = f2bf(wo[k * KD + d]);
  }
  if (t < 128) biaspg[t] = (t < 64) ? bc1[t] : bg1[t - 64];
}

// ---------------- passA: P[r][NOUT] = X[r][0:64] @ Wseg (+bias), bf16 out ------
template<int NOUT>
__global__ __launch_bounds__(256) void k_partial(
    const float* __restrict__ X, const unsigned short* __restrict__ wfrag,
    const float* __restrict__ bias, unsigned short* __restrict__ P, int nrows) {
  constexpr int NSH = NOUT * 64;               // shorts in frag table
  __shared__ unsigned short wl[NSH];
  const int tid = threadIdx.x;
  for (int c = tid * 8; c < NSH; c += 256 * 8)
    *(bf16x8*)&wl[c] = *(const bf16x8*)&wfrag[c];
  __syncthreads();
  const int wave = tid >> 6, lane = tid & 63, p = lane >> 4, q = lane & 15;
  const int ntile = (nrows + 63) >> 6;
  for (int tile = blockIdx.x; tile < ntile; tile += gridDim.x) {
    const int r0 = tile * 64 + wave * 16 + q;
    const int r = (r0 < nrows) ? r0 : (nrows - 1);
    bf16x8 b[2];
    b[0] = pack8(X + (long)r * 64 + 8 * p);
    b[1] = pack8(X + (long)r * 64 + 32 + 8 * p);
    unsigned short* dst = P + (long)r0 * NOUT;
#pragma unroll
    for (int n = 0; n < NOUT / 16; n++) {
      f32x4 acc;
      if (bias) acc = (f32x4&)*(const float4*)(bias + 16 * n + 4 * p);
      else      acc = (f32x4){0.f, 0.f, 0.f, 0.f};
#pragma unroll
      for (int s = 0; s < 2; s++) {
        bf16x8 a = *(const bf16x8*)&wl[((n * 2 + s) * 64 + lane) * 8];
        acc = __builtin_amdgcn_mfma_f32_16x16x32_bf16(a, b[s], acc, 0, 0, 0);
      }
      if (r0 < nrows) {
        ushort4 st = { f2bf(acc[0]), f2bf(acc[1]), f2bf(acc[2]), f2bf(acc[3]) };
        *(ushort4*)(dst + 16 * n + 4 * p) = st;
      }
    }
  }
}

// ---------------- passB: gather partials -> silu -> GEMM2 -> atomic scatter ----
__global__ __launch_bounds__(256) void k_angle2(
    const int* __restrict__ bgr,
    const unsigned short* __restrict__ PB, const unsigned short* __restrict__ PA,
    const unsigned short* __restrict__ PG,
    const unsigned short* __restrict__ wc2t, const unsigned short* __restrict__ wg2t,
    const float* __restrict__ bc2, const float* __restrict__ bg2,
    const float* __restrict__ bwt, float* __restrict__ agg, int ng, int na) {
  const int tid = threadIdx.x, wave = tid >> 6, lane = tid & 63;
  const int p = lane >> 4, q = lane & 15;
  const int g0 = blockIdx.x * 64 + wave * 16 + q;
  const int g = (g0 < ng) ? g0 : (ng - 1);
  const int ci0 = bgr[3 * g + 0];
  const int bi = bgr[3 * g + 1];
  const int bj = bgr[3 * g + 2];
  const int ci = min(ci0, na - 1);
  const int bic = min(bi, na - 1);
  const int bjc = min(bj, na - 1);

  const unsigned short* rb1 = PB + (long)bic * 256;        // [c64|g64|...]
  const unsigned short* rb2 = PB + (long)bjc * 256 + 128;  // PB2 at +128
  const unsigned short* ra  = PA + (long)ci * 128;
  const unsigned short* rg  = PG + (long)g * 128;
  const int o8 = 8 * p;

  // hidden = silu(PB1 + PB2 + PA + PG), lane holds k-slots 32s+8p+e
  bf16x8 b2c[2], b2g[2];
#pragma unroll
  for (int s = 0; s < 2; s++) {
    const int oo = o8 + 32 * s;
    bf16x8 f1 = *(const bf16x8*)(rb1 + oo);
    bf16x8 f2 = *(const bf16x8*)(rb2 + oo);
    bf16x8 f3 = *(const bf16x8*)(ra + oo);
    bf16x8 f4 = *(const bf16x8*)(rg + oo);
    bf16x8 g1 = *(const bf16x8*)(rb1 + 64 + oo);
    bf16x8 g2 = *(const bf16x8*)(rb2 + 64 + oo);
    bf16x8 g3 = *(const bf16x8*)(ra + 64 + oo);
    bf16x8 g4 = *(const bf16x8*)(rg + 64 + oo);
#pragma unroll
    for (int e = 0; e < 8; e++) {
      float x = bf2f((unsigned short)f1[e]) + bf2f((unsigned short)f2[e]) +
                bf2f((unsigned short)f3[e]) + bf2f((unsigned short)f4[e]);
      float y = bf2f((unsigned short)g1[e]) + bf2f((unsigned short)g2[e]) +
                bf2f((unsigned short)g3[e]) + bf2f((unsigned short)g4[e]);
      b2c[s][e] = (short)f2bf(silu_(x));
      b2g[s][e] = (short)f2bf(silu_(y));
    }
  }

  // GEMM2 (transposed): oc[n2][j] = O[d=16n2+4p+j][angle q]
  f32x4 oc[4], og[4];
#pragma unroll
  for (int n2 = 0; n2 < 4; n2++) {
    oc[n2] = (f32x4&)*(const float4*)(bc2 + 16 * n2 + 4 * p);
    og[n2] = (f32x4&)*(const float4*)(bg2 + 16 * n2 + 4 * p);
  }
#pragma unroll
  for (int s = 0; s < 2; s++) {
    const int ko = 32 * s + 8 * p;
#pragma unroll
    for (int n2 = 0; n2 < 4; n2++) {
      bf16x8 a1 = *(const bf16x8*)(wc2t + (q + 16 * n2) * KH + ko);
      oc[n2] = __builtin_amdgcn_mfma_f32_16x16x32_bf16(a1, b2c[s], oc[n2], 0, 0, 0);
      bf16x8 a2 = *(const bf16x8*)(wg2t + (q + 16 * n2) * KH + ko);
      og[n2] = __builtin_amdgcn_mfma_f32_16x16x32_bf16(a2, b2g[s], og[n2], 0, 0, 0);
    }
  }

  // epilogue: agg[bi][d] += silu(oc)*sigm(og)*bw[bi][d]*bw[bj][d]
  if (g0 < ng) {
    float* dst = agg + (long)bi * KD;
    const float* w1 = bwt + (long)bic * KD;
    const float* w2 = bwt + (long)bjc * KD;
#pragma unroll
    for (int n2 = 0; n2 < 4; n2++) {
      const int d = 16 * n2 + 4 * p;
      float4 wa = *(const float4*)(w1 + d);
      float4 wb = *(const float4*)(w2 + d);
      atomic_fadd(dst + d + 0, silu_(oc[n2][0]) * sigm(og[n2][0]) * wa.x * wb.x);
      atomic_fadd(dst + d + 1, silu_(oc[n2][1]) * sigm(og[n2][1]) * wa.y * wb.y);
      atomic_fadd(dst + d + 2, silu_(oc[n2][2]) * sigm(og[n2][2]) * wa.z * wb.z);
      atomic_fadd(dst + d + 3, silu_(oc[n2][3]) * sigm(og[n2][3]) * wa.w * wb.w);
    }
  }
}

// ---------------- K2: out = agg @ Wo + bo + bond (in place on d_out) ----------
__global__ __launch_bounds__(256) void k_out(
    const float* __restrict__ bond, const unsigned short* __restrict__ wot,
    const float* __restrict__ bo, float* __restrict__ out, int nb) {
  const int wave = threadIdx.x >> 6;
  const int lane = threadIdx.x & 63;
  const int r15 = lane & 15;
  const int ck = lane >> 4;
  const long rbase = (long)blockIdx.x * 64 + wave * 16;

  const long row = rbase + r15;
  const long rowc = (row < nb) ? row : 0;
  bf16x8 a[2];
  a[0] = pack8(out + rowc * KD + ck * 8);
  a[1] = pack8(out + rowc * KD + 32 + ck * 8);

  f32x4 acc[4];
#pragma unroll
  for (int n = 0; n < 4; n++) {
    float b = bo[n * 16 + r15];
    acc[n] = (f32x4){b, b, b, b};
  }
#pragma unroll
  for (int s = 0; s < 2; s++) {
    const int koff = s * 32 + ck * 8;
#pragma unroll
    for (int n = 0; n < 4; n++) {
      bf16x8 bf = *(const bf16x8*)(wot + (n * 16 + r15) * KH + koff);
      acc[n] = __builtin_amdgcn_mfma_f32_16x16x32_bf16(a[s], bf, acc[n], 0, 0, 0);
    }
  }
#pragma unroll
  for (int n = 0; n < 4; n++) {
#pragma unroll
    for (int j = 0; j < 4; j++) {
      const long orow = rbase + ck * 4 + j;
      if (orow < nb) {
        const int d = n * 16 + r15;
        out[orow * KD + d] = acc[n][j] + bond[orow * KD + d];
      }
    }
  }
}

extern "C" void kernel_launch(void* const* d_in, const int* in_sizes, int n_in,
                              void* d_out, int out_size, void* d_ws, size_t ws_size,
                              hipStream_t stream) {
  const float* atom = (const float*)d_in[0];
  const float* bond = (const float*)d_in[1];
  const float* bwt  = (const float*)d_in[2];
  const float* ang  = (const float*)d_in[3];
  const int*   bgr  = (const int*)d_in[4];
  const float* wc1 = (const float*)d_in[5];
  const float* bc1 = (const float*)d_in[6];
  const float* wc2 = (const float*)d_in[7];
  const float* bc2 = (const float*)d_in[8];
  const float* wg1 = (const float*)d_in[9];
  const float* bg1 = (const float*)d_in[10];
  const float* wg2 = (const float*)d_in[11];
  const float* bg2 = (const float*)d_in[12];
  const float* wo  = (const float*)d_in[13];
  const float* bo  = (const float*)d_in[14];

  const int na = in_sizes[0] / KD;   // atoms (40000) — bond_graph indices < na
  const int nb = in_sizes[1] / KD;   // bonds (200000)
  const int ng = in_sizes[4] / 3;    // angles (500000)
  float* out = (float*)d_out;

  char* pp = (char*)d_ws;
  auto alloc = [&](size_t bytes) { char* r = pp; pp += (bytes + 255) & ~(size_t)255; return r; };
  unsigned short* wpb  = (unsigned short*)alloc(16384 * 2);
  unsigned short* wpa  = (unsigned short*)alloc(8192 * 2);
  unsigned short* wpg  = (unsigned short*)alloc(8192 * 2);
  unsigned short* wc2t = (unsigned short*)alloc((size_t)KH * KD * 2);
  unsigned short* wg2t = (unsigned short*)alloc((size_t)KH * KD * 2);
  unsigned short* wot  = (unsigned short*)alloc((size_t)KH * KD * 2);
  float* biaspg        = (float*)alloc(128 * 4);
  unsigned short* PB   = (unsigned short*)alloc((size_t)na * 256 * 2);  // 20.5 MB
  unsigned short* PA   = (unsigned short*)alloc((size_t)na * 128 * 2);  // 10.2 MB
  unsigned short* PG   = (unsigned short*)alloc((size_t)ng * 128 * 2);  // 128 MB

  // d_out doubles as the aggregation buffer
  hipMemsetAsync(d_out, 0, (size_t)out_size * sizeof(float), stream);

  k_prep<<<64, 256, 0, stream>>>(wc1, wg1, wc2, wg2, wo, bc1, bg1,
                                 wpb, wpa, wpg, wc2t, wg2t, wot, biaspg);

  const int tb = (na + 63) / 64;                       // 625
  k_partial<256><<<tb, 256, 0, stream>>>(bond, wpb, (const float*)nullptr, PB, na);
  k_partial<128><<<tb, 256, 0, stream>>>(atom, wpa, (const float*)nullptr, PA, na);
  const int tg = (ng + 63) / 64;
  k_partial<128><<<(tg < 2048 ? tg : 2048), 256, 0, stream>>>(ang, wpg, biaspg, PG, ng);

  k_angle2<<<tg, 256, 0, stream>>>(bgr, PB, PA, PG, wc2t, wg2t,
                                   bc2, bg2, bwt, out, ng, na);

  k_out<<<(nb + 63) / 64, 256, 0, stream>>>(bond, wot, bo, out, nb);
}